// Round 14
// baseline (48.374 us; speedup 1.0000x reference)
//
#include <hip/hip_runtime.h>

#define BB 128
#define NN 16384
#define CC 8
#define WW 10
#define LL 16375            // N - W + 1
#define NT 512              // n's per block tile
#define NTILES (NN / NT)    // 32
#define BT 4                // b's per k_fir block
#define BTILES (BB / BT)    // 32
#define WSL (NT + 9)        // 521 staged taps per channel
#define SWSZ (WSL * 16 + 16)
#define BPB 2               // b per k_nonlin block
#define ABLK (BB / BPB)     // 64

typedef float f4_t __attribute__((ext_vector_type(4)));

// ---------------------------------------------------------------------------
// K1: FIR — the R8-measured kernel (25.3 us warm via double-launch probe):
// 256 threads, BT=4, 1024 blocks, f4 x-loads, LDS-staged taps, 16-slot
// register window, pk-FMA. ONLY change: final store goes to the TRANSPOSED
// fpart2[r][b][nt] layout so k_nonlin's gather is dense 128B runs.
// ---------------------------------------------------------------------------
__global__ __launch_bounds__(256) void k_fir(const float* __restrict__ x,
                                             const float* __restrict__ wr,
                                             const float* __restrict__ wi,
                                             float* __restrict__ fpart2) {
  __shared__ float smem[SWSZ];   // 33.4 KB; weights, later aliased as reduce buf
  f4_t* sw = (f4_t*)smem;

  int nt = blockIdx.x & (NTILES - 1);
  int bt = blockIdx.x >> 5;               // NTILES = 32
  int tid = threadIdx.x;
  int ntile = nt * NT;
  int l0 = ntile - 9;

  // ---- stage weights: sw[j*4 + c2] = {wr[2c2][l], wi[2c2][l], wr[2c2+1][l], wi[2c2+1][l]} ----
  {
    int c2s = tid >> 6;                    // 4 channel-pair groups x 64 lanes
    int ca = 2 * c2s, cb = 2 * c2s + 1;
    for (int j = tid & 63; j < WSL; j += 64) {   // coalesced along l
      int l = l0 + j;
      f4_t v = (f4_t)0.f;
      if (l >= 0 && l < LL) {
        v[0] = wr[(size_t)ca * LL + l];
        v[1] = wi[(size_t)ca * LL + l];
        v[2] = wr[(size_t)cb * LL + l];
        v[3] = wi[(size_t)cb * LL + l];
      }
      sw[j * 4 + c2s] = v;
    }
  }
  __syncthreads();

  int c2   = tid & 3;
  int bsub = (tid >> 2) & 3;
  int nh   = tid >> 4;                    // 0..15, 32-n slice
  int b    = bt * BT + bsub;
  int n0   = ntile + nh * 32;

  const f4_t* __restrict__ xp = ((const f4_t*)x) + ((size_t)b * NN + n0) * 4 + c2;
  const f4_t* swp = sw + (nh * 32 + 9) * 4 + c2;   // swp[4*t] = tap at n0 + t

  f4_t acc[WW];
#pragma unroll
  for (int w = 0; w < WW; ++w) acc[w] = (f4_t)0.f;

  f4_t wv[16];
  // preload slots 7..15 = taps n0-9 .. n0-1 (zero-padded in LDS)
#pragma unroll
  for (int k = 0; k < 9; ++k) wv[7 + k] = swp[4 * (k - 9)];

#pragma unroll
  for (int g = 0; g < 2; ++g) {
    // load slots 0..6 = taps nb .. nb+6 (their old contents are dead)
#pragma unroll
    for (int j = 0; j < 7; ++j) wv[j] = swp[4 * (16 * g + j)];
#pragma unroll
    for (int u = 0; u < 16; ++u) {
      f4_t xv = xp[(size_t)(16 * g + u) * 4];
#pragma unroll
      for (int w = 0; w < WW; ++w) {
        f4_t wt = wv[(u - w + 16) & 15];
        acc[w] += xv * wt;               // v_pk_fma_f32 x2
      }
      // slot u+7 (old tap nb-9+u) is last consumed at iteration u; refill now
      if (u <= 8) wv[u + 7] = swp[4 * (16 * g + u + 7)];
    }
  }

  // ---- reduce over nh bits 0,1 (= lane bits 4,5) in-register ----
#pragma unroll
  for (int w = 0; w < WW; ++w)
#pragma unroll
    for (int e = 0; e < 4; ++e) {
      acc[w][e] += __shfl_xor(acc[w][e], 16);
      acc[w][e] += __shfl_xor(acc[w][e], 32);
    }

  __syncthreads();                        // weight reads done; alias smem as reduce buf
  int wave = tid >> 6, lane = tid & 63;
  if (lane < 16) {                        // lane = c2 + 4*bsub
#pragma unroll
    for (int w = 0; w < WW; ++w)
      *(f4_t*)&smem[(wave * 16 + lane) * 40 + w * 4] = acc[w];
  }
  __syncthreads();
  // final: sum the 4 waves (nh bits 2,3); store TRANSPOSED fpart2[r][b][nt]
  for (int t = tid; t < BT * 160; t += 256) {
    int bs = t / 160;
    int r  = t - bs * 160;               // r = w*16 + cc*2 + ri
    int w  = r >> 4;
    int cc = (r >> 1) & 7;
    int ri = r & 1;
    int ln = (cc >> 1) + 4 * bs;
    int e  = (cc & 1) * 2 + ri;
    float s = 0.f;
#pragma unroll
    for (int wv_ = 0; wv_ < 4; ++wv_) s += smem[(wv_ * 16 + ln) * 40 + w * 4 + e];
    fpart2[((size_t)r * BB + (bt * BT + bs)) * NTILES + nt] = s;
  }
}

// ---------------------------------------------------------------------------
// K2: nonlin + projection — byte-identical to R13 (passed, absmax 0.0).
// Dense gather: thread-iter (r, bl) reads 8 consecutive float4 of fpart2.
// ---------------------------------------------------------------------------
__global__ __launch_bounds__(256) void k_nonlin(const float* __restrict__ fpart2,
                                                const float* __restrict__ wc,
                                                const float* __restrict__ wor,
                                                const float* __restrict__ woi,
                                                float* __restrict__ oraw,
                                                float* __restrict__ part) {
  __shared__ float sred[BPB][164];
  __shared__ float swc[672];
  __shared__ float swout[160];       // [p][c][w]

  int tid = threadIdx.x;
  int blk = blockIdx.x;
  int b0 = blk * BPB;

  for (int i = tid; i < 672; i += 256) swc[i] = wc[i];
  if (tid < 80) swout[tid] = wor[tid];
  else if (tid < 160) swout[tid] = woi[tid - 80];

  // dense stage: r = row (0..159), bl = batch-in-block; 8 consecutive f4 each
  for (int t = tid; t < 2 * 160; t += 256) {
    int r = t >> 1, bl = t & 1;
    const f4_t* fp = (const f4_t*)(fpart2 + ((size_t)r * BB + b0 + bl) * NTILES);
    f4_t s4 = (f4_t)0.f;
#pragma unroll
    for (int k = 0; k < NTILES / 4; ++k) s4 += fp[k];
    sred[bl][r] = s4[0] + s4[1] + s4[2] + s4[3];
  }
  __syncthreads();

  if (tid < 32) {
    int bl = tid >> 4;
    int c  = (tid >> 1) & 7;
    int p  = tid & 1;

    float wreg[8][2][3];
#pragma unroll
    for (int j = 0; j < 8; ++j) {
      int jj = j - (j > c ? 1 : 0);
      if (j == c) jj = 0;
#pragma unroll
      for (int ri = 0; ri < 2; ++ri)
#pragma unroll
        for (int d = 0; d < 3; ++d) {
          float v = swc[(c * 2 + p) * 42 + ri * 21 + jj * 3 + d];
          wreg[j][ri][d] = (j == c) ? 0.f : v;
        }
    }

    float o = 0.f;
    const float* wop = swout + p * 80 + c * 10;
#pragma unroll
    for (int w = 0; w < WW; ++w) {
      float4 f0 = *(const float4*)&sred[bl][w * 16];
      float4 f1 = *(const float4*)&sred[bl][w * 16 + 4];
      float4 f2 = *(const float4*)&sred[bl][w * 16 + 8];
      float4 f3 = *(const float4*)&sred[bl][w * 16 + 12];
      float fv[16] = {f0.x, f0.y, f0.z, f0.w, f1.x, f1.y, f1.z, f1.w,
                      f2.x, f2.y, f2.z, f2.w, f3.x, f3.y, f3.z, f3.w};
      float nl0 = 0.f, nl1 = 0.f, nl2 = 0.f;
#pragma unroll
      for (int j = 0; j < 8; ++j) {
        float r  = fv[2 * j];
        float im = fv[2 * j + 1];
        float r2 = r * r, i2 = im * im;
        float pw0 = r + im;
        float pw1 = r2 + i2;
        float pw2 = r2 * r + i2 * im;
        nl0 += (pw0 * r) * wreg[j][0][0] + (pw0 * im) * wreg[j][1][0];
        nl1 += (pw1 * r) * wreg[j][0][1] + (pw1 * im) * wreg[j][1][1];
        nl2 += (pw2 * r) * wreg[j][0][2] + (pw2 * im) * wreg[j][1][2];
      }
      o += (nl0 + nl1 + nl2) * wop[w];
    }

    oraw[((size_t)(b0 + bl) * CC + c) * 2 + p] = o;

    float s = o, q = o * o;
    s += __shfl_xor(s, 1);  q += __shfl_xor(q, 1);
    s += __shfl_xor(s, 16); q += __shfl_xor(q, 16);
    if ((tid & 17) == 0) {             // p==0 && bl==0 -> tid = c*2
      part[blk * 16 + c * 2 + 0] = s;
      part[blk * 16 + c * 2 + 1] = q;
    }
  }
}

// ---------------------------------------------------------------------------
// K3: BatchNorm finalize — byte-identical to R13. 1 block x 256 threads.
// ---------------------------------------------------------------------------
__global__ __launch_bounds__(256) void k_bn(const float* __restrict__ oraw,
                                            const float* __restrict__ part,
                                            const float* __restrict__ gamma,
                                            const float* __restrict__ beta,
                                            float* __restrict__ out) {
  __shared__ float mv[8], iv[8], bv[8];
  int tid = threadIdx.x;
  if (tid < 16) {
    int cc = tid >> 1, qq = tid & 1;
    float s = 0.f;
#pragma unroll
    for (int k = 0; k < ABLK; ++k) s += part[k * 16 + cc * 2 + qq];
    float other = __shfl_xor(s, 1);
    if (qq == 0) {
      float mean = s * (1.0f / 256.0f);
      float var  = other * (1.0f / 256.0f) - mean * mean;
      mv[cc] = mean;
      iv[cc] = gamma[cc] * rsqrtf(var + 1e-5f);
      bv[cc] = beta[cc];
    }
  }
  __syncthreads();
  for (int i = tid; i < BB * CC * 2; i += 256) {
    int c = (i >> 1) & 7;
    out[i] = (oraw[i] - mv[c]) * iv[c] + bv[c];
  }
}

// ---------------------------------------------------------------------------
extern "C" void kernel_launch(void* const* d_in, const int* in_sizes, int n_in,
                              void* d_out, int out_size, void* d_ws, size_t ws_size,
                              hipStream_t stream) {
  const float* x   = (const float*)d_in[0];
  const float* wr  = (const float*)d_in[1];
  const float* wi  = (const float*)d_in[2];
  const float* wc  = (const float*)d_in[3];
  const float* wor = (const float*)d_in[4];
  const float* woi = (const float*)d_in[5];
  const float* gm  = (const float*)d_in[6];
  const float* bt  = (const float*)d_in[7];
  float* out = (float*)d_out;

  float* ws     = (float*)d_ws;
  float* fpart2 = ws;                                   // 160*BB*NTILES = 655360 f32
  float* oraw   = fpart2 + (size_t)160 * BB * NTILES;   // 2048 f32
  float* part   = oraw + BB * CC * 2;                   // ABLK*16 = 1024 f32

  k_fir<<<dim3(BTILES * NTILES), dim3(256), 0, stream>>>(x, wr, wi, fpart2);
  k_nonlin<<<dim3(ABLK), dim3(256), 0, stream>>>(fpart2, wc, wor, woi, oraw, part);
  k_bn<<<dim3(1), dim3(256), 0, stream>>>(oraw, part, gm, bt, out);
}